// Round 2
// baseline (210.620 us; speedup 1.0000x reference)
//
#include <hip/hip_runtime.h>

// Problem constants (from reference): x [B, NF, T] f32, durations [B, N] int
#define BB 64
#define NF 64
#define TT 8192
#define NN 1024

// Kernel 1: per-batch inclusive scan of durations -> boundaries[b][0..N]
// boundaries[b][0] = 0, boundaries[b][n+1] = cumsum(dur[b][0..n])
__global__ __launch_bounds__(NN) void scan_kernel(const int* __restrict__ dur,
                                                  int* __restrict__ bnd) {
    const int b = blockIdx.x;
    const int t = threadIdx.x;
    __shared__ int s[NN];
    s[t] = dur[b * NN + t];
    __syncthreads();
    // Hillis-Steele inclusive scan, 10 steps
    for (int off = 1; off < NN; off <<= 1) {
        int v = (t >= off) ? s[t - off] : 0;
        __syncthreads();
        s[t] += v;
        __syncthreads();
    }
    bnd[b * (NN + 1) + t + 1] = s[t];
    if (t == 0) bnd[b * (NN + 1)] = 0;
}

// Kernel 2: one block per (b, nf) row. Stage row in LDS (coalesced float4),
// stage boundaries, then each thread averages its tokens' segments.
__global__ __launch_bounds__(256) void avg_kernel(const float* __restrict__ x,
                                                  const int* __restrict__ bnd,
                                                  float* __restrict__ out) {
    const int row = blockIdx.x;          // b*NF + nf
    const int b   = row / NF;
    const int t   = threadIdx.x;

    __shared__ float xs[TT];             // 32 KiB
    __shared__ int   bs[NN + 1];         // 4.1 KiB

    // stage boundaries (reused across 64 blocks per batch -> L2 hits)
    for (int i = t; i < NN + 1; i += 256) bs[i] = bnd[b * (NN + 1) + i];

    // stage x row: 2048 float4s / 256 threads = 8 iters, fully coalesced
    const float4* xv  = (const float4*)(x + (size_t)row * TT);
    float4*       xsv = (float4*)xs;
#pragma unroll
    for (int i = 0; i < TT / 4 / 256; ++i) xsv[t + i * 256] = xv[t + i * 256];
    __syncthreads();

    float* orow = out + (size_t)row * NN;
#pragma unroll
    for (int k = 0; k < NN / 256; ++k) {
        const int n  = t + k * 256;
        const int s0 = bs[n];
        const int e0 = bs[n + 1];
        float sum = 0.0f;
        int   cnt = 0;
        for (int i = s0; i < e0; ++i) {
            float v = xs[i];
            sum += v;
            cnt += (v != 0.0f) ? 1 : 0;
        }
        orow[n] = (cnt != 0) ? (sum / (float)cnt) : 0.0f;
    }
}

extern "C" void kernel_launch(void* const* d_in, const int* in_sizes, int n_in,
                              void* d_out, int out_size, void* d_ws, size_t ws_size,
                              hipStream_t stream) {
    const float* x   = (const float*)d_in[0];
    const int*   dur = (const int*)d_in[1];   // harness delivers integer inputs as int32
    float*       out = (float*)d_out;
    int*         bnd = (int*)d_ws;            // B*(N+1) int32 = 262,400 B scratch

    scan_kernel<<<BB, NN, 0, stream>>>(dur, bnd);
    avg_kernel<<<BB * NF, 256, 0, stream>>>(x, bnd, out);
}

// Round 4
// 203.920 us; speedup vs baseline: 1.0329x; 1.0329x over previous
//
#include <hip/hip_runtime.h>

// Problem constants (from reference): x [B, NF, T] f32, durations [B, N] int
#define BB 64
#define NF 64
#define TT 8192
#define NN 1024
#define G  (TT / 4)              // 2048 granules of 4 floats
#define PAD(c) ((c) + ((c) >> 3))   // +1 slot per 8 -> read addr 9t+j, conflict-free
#define CSZ (PAD(G) + 1)         // 2305 slots (includes grand-total slot at PAD(G))

// Kernel 1: per-batch inclusive scan of durations -> boundaries[b][0..N]
__global__ __launch_bounds__(NN) void scan_kernel(const int* __restrict__ dur,
                                                  int* __restrict__ bnd) {
    const int b = blockIdx.x;
    const int t = threadIdx.x;
    __shared__ int s[NN];
    s[t] = dur[b * NN + t];
    __syncthreads();
    for (int off = 1; off < NN; off <<= 1) {
        int v = (t >= off) ? s[t - off] : 0;
        __syncthreads();
        s[t] += v;
        __syncthreads();
    }
    bnd[b * (NN + 1) + t + 1] = s[t];
    if (t == 0) bnd[b * (NN + 1)] = 0;
}

// Kernel 2: one block per (b, nf) row. Prefix-sum formulation (no serial walks):
//   A: stream row (float4), granule sums/counts -> padded LDS; raw granules kept.
//   B: block exclusive scan of 2048 granule sums (reg scan + wave shfl + combine).
//   C: prefix value at each of 1025 boundaries (1 LDS read + <=3 predicated adds).
//   D: token mean = adjacent prefix difference, coalesced store.
__global__ __launch_bounds__(256) void avg_kernel(const float* __restrict__ x,
                                                  const int* __restrict__ bnd,
                                                  float* __restrict__ out) {
    const int row  = blockIdx.x;          // b*NF + nf
    const int b    = row / NF;
    const int t    = threadIdx.x;
    const int lane = t & 63;
    const int w    = t >> 6;

    __shared__ float4 xg[G];              // raw granules, 32 KiB
    __shared__ float  csum[CSZ];          // granule sums -> exclusive scan, 9.2 KiB
    __shared__ int    ccnt[CSZ];          // granule nonzero counts -> scan, 9.2 KiB
    __shared__ float  P[NN + 1];          // prefix sum at boundaries
    __shared__ float  Kc[NN + 1];         // prefix count at boundaries
    __shared__ float  wsumf[4];
    __shared__ int    wsumi[4];

    // ---- Phase A: stage + granule sums (coalesced float4) ----
    const float4* xv = (const float4*)(x + (size_t)row * TT);
#pragma unroll
    for (int k = 0; k < G / 256; ++k) {
        const int c = t + k * 256;
        float4 v = xv[c];
        xg[c] = v;
        csum[PAD(c)] = v.x + v.y + v.z + v.w;
        ccnt[PAD(c)] = (v.x != 0.f) + (v.y != 0.f) + (v.z != 0.f) + (v.w != 0.f);
    }
    __syncthreads();

    // ---- Phase B: block exclusive scan over 2048 granules; thread t owns [8t, 8t+8) ----
    float sv[8]; int cv[8];
    float fs = 0.f; int cs = 0;
#pragma unroll
    for (int j = 0; j < 8; ++j) {
        const int c = 8 * t + j;          // PAD(c) = 9t + j : all 32 banks, conflict-free
        fs += csum[PAD(c)];
        cs += ccnt[PAD(c)];
        sv[j] = fs; cv[j] = cs;           // within-thread inclusive
    }
    float ws = fs; int wc = cs;           // wave64 inclusive scan of per-thread totals
#pragma unroll
    for (int d = 1; d < 64; d <<= 1) {
        float uf = __shfl_up(ws, d, 64);
        int   ui = __shfl_up(wc, d, 64);
        if (lane >= d) { ws += uf; wc += ui; }
    }
    if (lane == 63) { wsumf[w] = ws; wsumi[w] = wc; }
    __syncthreads();
    float woff = 0.f; int coff = 0;
#pragma unroll
    for (int i = 0; i < 4; ++i) if (i < w) { woff += wsumf[i]; coff += wsumi[i]; }
    const float base  = woff + (ws - fs); // exclusive prefix for this thread's chunk
    const int   cbase = coff + (wc - cs);
#pragma unroll
    for (int j = 0; j < 8; ++j) {
        const int c = 8 * t + j;
        csum[PAD(c)] = base  + (j ? sv[j - 1] : 0.f);   // exclusive per-granule
        ccnt[PAD(c)] = cbase + (j ? cv[j - 1] : 0);
    }
    if (t == 255) { csum[PAD(G)] = woff + ws; ccnt[PAD(G)] = coff + wc; }
    __syncthreads();

    // ---- Phase C: prefix at each boundary position ----
    const int* brow = bnd + b * (NN + 1);
    for (int i = t; i <= NN; i += 256) {
        const int p = brow[i];            // position in [0, T]
        const int g = p >> 2, r = p & 3;
        float4 v = xg[g & (G - 1)];       // masked index; unused when r==0
        float part = 0.f; int pc = 0;
        if (r > 0) { part += v.x; pc += (v.x != 0.f); }
        if (r > 1) { part += v.y; pc += (v.y != 0.f); }
        if (r > 2) { part += v.z; pc += (v.z != 0.f); }
        P[i]  = csum[PAD(g)] + part;      // p==T -> g==G -> grand-total slot, r==0
        Kc[i] = (float)(ccnt[PAD(g)] + pc);
    }
    __syncthreads();

    // ---- Phase D: token means, coalesced ----
    float* orow = out + (size_t)row * NN;
#pragma unroll
    for (int k = 0; k < NN / 256; ++k) {
        const int n = t + k * 256;
        const float s = P[n + 1] - P[n];
        const float c = Kc[n + 1] - Kc[n];
        orow[n] = (c != 0.f) ? (s / c) : 0.f;
    }
}

extern "C" void kernel_launch(void* const* d_in, const int* in_sizes, int n_in,
                              void* d_out, int out_size, void* d_ws, size_t ws_size,
                              hipStream_t stream) {
    const float* x   = (const float*)d_in[0];
    const int*   dur = (const int*)d_in[1];
    float*       out = (float*)d_out;
    int*         bnd = (int*)d_ws;        // B*(N+1) int32 = 262,400 B scratch

    scan_kernel<<<BB, NN, 0, stream>>>(dur, bnd);
    avg_kernel<<<BB * NF, 256, 0, stream>>>(x, bnd, out);
}